// Round 7
// baseline (169.641 us; speedup 1.0000x reference)
//
#include <hip/hip_runtime.h>

// MHA forward: S=2048, B=4, E=512, H=8, D=64.
// qkv_kernel (3x GEMM) -> attn_kernel (flash) -> oproj_kernel.
// R7: attn is L2-miss-path BW-bound (786 MB/invocation, mask fp32 read 8x =
// 512 MB of it). Fix: (1) 2 heads per block -> both heads' waves share the
// mask tile via L1/L2 (mask path traffic halves); (2) XCD-aware blockIdx
// swizzle so all 32 q-tile blocks of a head-pair land on one XCD -> K/V
// (2 MB/XCD) становится L2-resident. Core compute stays R5: 32x32x16 MFMA,
// swapped QK^T, in-register P (cvt_pk + permlane32_swap), fixed-ref softmax,
// dbuf K/V LDS (XOR swizzle), 1 barrier/tile, reg prefetch.

#define L2E 1.44269504088896340736f

typedef __attribute__((ext_vector_type(8))) __bf16 bf16x8;
typedef __attribute__((ext_vector_type(4))) float f32x4;
typedef __attribute__((ext_vector_type(16))) float f32x16;

// packed bf16 pair via native casts (compiler emits v_cvt_pk_bf16_f32)
static __device__ __forceinline__ unsigned pk2(float a, float b) {
    union { unsigned u; __bf16 h[2]; } cv;
    cv.h[0] = (__bf16)a; cv.h[1] = (__bf16)b;
    return cv.u;
}

static __device__ __forceinline__ unsigned short f2bf(float f) {
    union { unsigned short s; __bf16 h; } cv;
    cv.h = (__bf16)f;
    return cv.s;
}

// ---------------------------------------------------------------------------
// Kernel 0: QKV projection. z selects (input, weight slice, dst).
//   z=0 -> Qp[bh][s][d] scaled by L2E/8 (folds softmax log2e), z=1 -> Kp,
//   z=2 -> Vt[bh][d][s] (transposed for PV A-operand).
// ---------------------------------------------------------------------------
__global__ __launch_bounds__(256) void qkv_kernel(
    const float* __restrict__ Xq, const float* __restrict__ Xk,
    const float* __restrict__ Xv, const float* __restrict__ W,
    const float* __restrict__ bias,
    unsigned short* __restrict__ Qp, unsigned short* __restrict__ Kp,
    unsigned short* __restrict__ Vt)
{
    __shared__ unsigned short lA[128][40];  // pad 32->40 shorts
    __shared__ unsigned short lB[128][40];

    const int z = blockIdx.z;
    const float* X  = (z == 0) ? Xq : (z == 1) ? Xk : Xv;
    const float* Wz = W + (size_t)z * 512 * 512;
    const int rb = blockIdx.y * 128;
    const int nb = blockIdx.x * 128;
    const int tid  = threadIdx.x;
    const int lane = tid & 63, wave = tid >> 6;
    const int wr = wave >> 1, wc = wave & 1;
    const int lq = lane & 15, lg = lane >> 4;

    f32x4 acc[4][4];
#pragma unroll
    for (int i = 0; i < 4; ++i)
#pragma unroll
        for (int j = 0; j < 4; ++j) acc[i][j] = (f32x4){0.f, 0.f, 0.f, 0.f};

    const int srow = tid >> 1;          // 0..127
    const int scol = (tid & 1) * 16;    // 0 or 16 (elements)

    for (int kt = 0; kt < 16; ++kt) {
        const int k0 = kt * 32;
        if (kt) __syncthreads();
        {   // A tile (fp32 -> bf16)
            const float* g = X + (size_t)(rb + srow) * 512 + k0 + scol;
            float4 x0 = *(const float4*)(g + 0);
            float4 x1 = *(const float4*)(g + 4);
            float4 x2 = *(const float4*)(g + 8);
            float4 x3 = *(const float4*)(g + 12);
            uint4 w0, w1;
            w0.x = pk2(x0.x, x0.y); w0.y = pk2(x0.z, x0.w);
            w0.z = pk2(x1.x, x1.y); w0.w = pk2(x1.z, x1.w);
            w1.x = pk2(x2.x, x2.y); w1.y = pk2(x2.z, x2.w);
            w1.z = pk2(x3.x, x3.y); w1.w = pk2(x3.z, x3.w);
            *(uint4*)&lA[srow][scol] = w0;
            *(uint4*)&lA[srow][scol + 8] = w1;
        }
        {   // B tile (weights fp32 -> bf16); W is [n][k], k contiguous
            const float* g = Wz + (size_t)(nb + srow) * 512 + k0 + scol;
            float4 x0 = *(const float4*)(g + 0);
            float4 x1 = *(const float4*)(g + 4);
            float4 x2 = *(const float4*)(g + 8);
            float4 x3 = *(const float4*)(g + 12);
            uint4 w0, w1;
            w0.x = pk2(x0.x, x0.y); w0.y = pk2(x0.z, x0.w);
            w0.z = pk2(x1.x, x1.y); w0.w = pk2(x1.z, x1.w);
            w1.x = pk2(x2.x, x2.y); w1.y = pk2(x2.z, x2.w);
            w1.z = pk2(x3.x, x3.y); w1.w = pk2(x3.z, x3.w);
            *(uint4*)&lB[srow][scol] = w0;
            *(uint4*)&lB[srow][scol + 8] = w1;
        }
        __syncthreads();

        bf16x8 af[4], bf[4];
#pragma unroll
        for (int mi = 0; mi < 4; ++mi)
            af[mi] = *(const bf16x8*)&lA[wr * 64 + mi * 16 + lq][lg * 8];
#pragma unroll
        for (int ni = 0; ni < 4; ++ni)
            bf[ni] = *(const bf16x8*)&lB[wc * 64 + ni * 16 + lq][lg * 8];
#pragma unroll
        for (int mi = 0; mi < 4; ++mi)
#pragma unroll
            for (int ni = 0; ni < 4; ++ni)
                acc[mi][ni] = __builtin_amdgcn_mfma_f32_16x16x32_bf16(
                    af[mi], bf[ni], acc[mi][ni], 0, 0, 0);
    }

    // epilogue: C layout col = lane&15 (n), row = (lane>>4)*4 + r (m)
    const float* bz = bias + z * 512;
#pragma unroll
    for (int ni = 0; ni < 4; ++ni) {
        const int n = nb + wc * 64 + ni * 16 + lq;
        const float bv = bz[n];
        const int h = n >> 6, d = n & 63;
#pragma unroll
        for (int mi = 0; mi < 4; ++mi) {
#pragma unroll
            for (int r = 0; r < 4; ++r) {
                const int t = rb + wr * 64 + mi * 16 + lg * 4 + r;
                float v = acc[mi][ni][r] + bv;
                const int s = t >> 2, b = t & 3;
                if (z == 0) {
                    v *= 0.125f * L2E;  // 1/sqrt(D) * log2(e)
                    Qp[((size_t)(b * 8 + h) * 2048 + s) * 64 + d] = f2bf(v);
                } else if (z == 1) {
                    Kp[((size_t)(b * 8 + h) * 2048 + s) * 64 + d] = f2bf(v);
                } else {
                    Vt[((size_t)(b * 8 + h) * 64 + d) * 2048 + s] = f2bf(v);
                }
            }
        }
    }
}

// ---------------------------------------------------------------------------
// Kernel 1: flash attention, 32x32x16 MFMA, swapped QK^T, 2 heads/block.
// grid = 512 1D, decoded: pair pr = (g&7)|((g>>8)<<3) (0..15), qt = (g>>3)&31.
// XCD swizzle: pair pr -> XCD pr&7 (g mod 8 == pr&7), so one XCD holds all
// 32 q-tile blocks of pairs {pr, pr+8}: K/V footprint 2 MB -> L2-resident.
// 4 waves: head = wave>>1 (within pair), qsub = wave&1 (32 q-rows each).
// Both heads' waves read the same mask floats (per-lane float4 -> C-init);
// L1 dedups the second read.
// ---------------------------------------------------------------------------
#define SWAP32(a, b) asm("v_permlane32_swap_b32 %0, %1" : "+v"(a), "+v"(b))

#define COMPUTE(KC, VC, M) do {                                                \
    bf16x8 pf[4];                                                              \
    _Pragma("unroll")                                                          \
    for (int kblk = 0; kblk < 2; ++kblk) {                                     \
        f32x16 z;                                                              \
        _Pragma("unroll")                                                      \
        for (int g = 0; g < 4; ++g) {                                          \
            z[4*g+0] = M[kblk][g].x * L2E;                                     \
            z[4*g+1] = M[kblk][g].y * L2E;                                     \
            z[4*g+2] = M[kblk][g].z * L2E;                                     \
            z[4*g+3] = M[kblk][g].w * L2E;                                     \
        }                                                                      \
        __builtin_amdgcn_s_setprio(1);                                         \
        _Pragma("unroll")                                                      \
        for (int s = 0; s < 4; ++s) {                                          \
            bf16x8 kf = *(const bf16x8*)((KC) + fof[kblk][s]);                 \
            z = __builtin_amdgcn_mfma_f32_32x32x16_bf16(kf, qf[s], z, 0,0,0);  \
        }                                                                      \
        __builtin_amdgcn_s_setprio(0);                                         \
        float p[16];                                                           \
        _Pragma("unroll")                                                      \
        for (int i = 0; i < 16; ++i) p[i] = exp2f(z[i]);                       \
        lsum += (((p[0]+p[1])+(p[2]+p[3])) + ((p[4]+p[5])+(p[6]+p[7])))        \
              + (((p[8]+p[9])+(p[10]+p[11])) + ((p[12]+p[13])+(p[14]+p[15]))); \
        unsigned a0 = pk2(p[0], p[1]),   b0 = pk2(p[4], p[5]);                 \
        unsigned a1 = pk2(p[2], p[3]),   b1 = pk2(p[6], p[7]);                 \
        SWAP32(a0, b0); SWAP32(a1, b1);                                        \
        union { unsigned w[4]; bf16x8 v; } u0;                                 \
        u0.w[0] = a0; u0.w[1] = a1; u0.w[2] = b0; u0.w[3] = b1;                \
        pf[kblk*2] = u0.v;                                                     \
        unsigned c0 = pk2(p[8], p[9]),   d0 = pk2(p[12], p[13]);               \
        unsigned c1 = pk2(p[10], p[11]), d1 = pk2(p[14], p[15]);               \
        SWAP32(c0, d0); SWAP32(c1, d1);                                        \
        union { unsigned w[4]; bf16x8 v; } u1;                                 \
        u1.w[0] = c0; u1.w[1] = c1; u1.w[2] = d0; u1.w[3] = d1;                \
        pf[kblk*2+1] = u1.v;                                                   \
    }                                                                          \
    __builtin_amdgcn_s_setprio(1);                                             \
    _Pragma("unroll")                                                          \
    for (int s = 0; s < 4; ++s) {                                              \
        bf16x8 vf0 = *(const bf16x8*)((VC) + fof[0][s]);                       \
        o0 = __builtin_amdgcn_mfma_f32_32x32x16_bf16(vf0, pf[s], o0, 0,0,0);   \
        bf16x8 vf1 = *(const bf16x8*)((VC) + fof[1][s]);                       \
        o1 = __builtin_amdgcn_mfma_f32_32x32x16_bf16(vf1, pf[s], o1, 0,0,0);   \
    }                                                                          \
    __builtin_amdgcn_s_setprio(0);                                             \
} while (0)

#define LOADNEXT(MDST) do {                                                    \
    ka0 = *(const uint4*)(pgK0); kc0 = *(const uint4*)(pgK0 + 8);              \
    ka1 = *(const uint4*)(pgK1); kc1 = *(const uint4*)(pgK1 + 8);              \
    va0 = *(const uint4*)(pgV0); vc0 = *(const uint4*)(pgV0 + 8);              \
    va1 = *(const uint4*)(pgV1); vc1 = *(const uint4*)(pgV1 + 8);              \
    _Pragma("unroll")                                                          \
    for (int kblk = 0; kblk < 2; ++kblk)                                       \
        _Pragma("unroll")                                                      \
        for (int g = 0; g < 4; ++g)                                            \
            MDST[kblk][g] = *(const float4*)(pm + kblk * 32 + g * 8);          \
    pgK0 += 4096; pgK1 += 4096; pgV0 += 64; pgV1 += 64; pm += 64;              \
} while (0)

#define STORE(BUF) do {                                                        \
    *(uint4*)&lK[BUF][0][srow][su0 * 8] = ka0;                                 \
    *(uint4*)&lK[BUF][0][srow][su1 * 8] = kc0;                                 \
    *(uint4*)&lK[BUF][1][srow][su0 * 8] = ka1;                                 \
    *(uint4*)&lK[BUF][1][srow][su1 * 8] = kc1;                                 \
    *(uint4*)&lV[BUF][0][srow][su0 * 8] = va0;                                 \
    *(uint4*)&lV[BUF][0][srow][su1 * 8] = vc0;                                 \
    *(uint4*)&lV[BUF][1][srow][su0 * 8] = va1;                                 \
    *(uint4*)&lV[BUF][1][srow][su1 * 8] = vc1;                                 \
} while (0)

__global__ __launch_bounds__(256, 2) void attn_kernel(
    const unsigned short* __restrict__ Qp, const unsigned short* __restrict__ Kp,
    const unsigned short* __restrict__ Vt, const float* __restrict__ mask,
    unsigned short* __restrict__ AO)
{
    __shared__ unsigned short lK[2][2][64][64];  // [buf][head][k][d], swizzled
    __shared__ unsigned short lV[2][2][64][64];  // [buf][head][d][k], swizzled

    const int g0 = blockIdx.x;
    const int pr = (g0 & 7) | ((g0 >> 8) << 3);   // head-pair 0..15
    const int qt = (g0 >> 3) & 31;                // q-tile (64 rows) 0..31
    const int b  = pr >> 2;
    const int h0 = (pr & 3) << 1;

    const int tid  = threadIdx.x;
    const int lane = tid & 63, wave = tid >> 6;
    const int lc = lane & 31, hi = lane >> 5;
    const int hw = wave >> 1;                     // head within pair
    const int qg = qt * 64 + (wave & 1) * 32 + lc;
    const int bh = b * 8 + h0 + hw;

    // Q B-fragments: lane needs Q[qg][s*16 + hi*8 + 0..7]
    bf16x8 qf[4];
    {
        const unsigned short* qp = Qp + ((size_t)bh * 2048 + qg) * 64 + hi * 8;
#pragma unroll
        for (int s = 0; s < 4; ++s)
            qf[s] = *(const bf16x8*)(qp + s * 16);
    }

    f32x16 o0, o1;
#pragma unroll
    for (int i = 0; i < 16; ++i) { o0[i] = 0.f; o1[i] = 0.f; }
    float lsum = 0.f;

    // K/V fragment byte-offsets in one head's [64][64]-short tile:
    // row = blk*32 + lc; 16B-unit = (2s|hi) ^ (row&7)
    int fof[2][4];
#pragma unroll
    for (int blk = 0; blk < 2; ++blk)
#pragma unroll
        for (int s = 0; s < 4; ++s)
            fof[blk][s] = (blk * 32 + lc) * 128 +
                          ((((s << 1) | hi) ^ (lane & 7)) * 16);

    const char* lK0c = (const char*)&lK[0][hw][0][0];
    const char* lK1c = (const char*)&lK[1][hw][0][0];
    const char* lV0c = (const char*)&lV[0][hw][0][0];
    const char* lV1c = (const char*)&lV[1][hw][0][0];

    // staging: thread owns row tid>>2 (of each head's K and V tile),
    // 16B-units (tid&3)*2 and +1, XOR-swizzled
    const int srow = tid >> 2;
    const int scu  = (tid & 3) * 2;
    const int su0  = (scu    ) ^ (srow & 7);
    const int su1  = (scu + 1) ^ (srow & 7);
    const unsigned short* pgK0 = Kp + (size_t)(b*8+h0  ) * 2048 * 64 + (size_t)srow * 64   + scu * 8;
    const unsigned short* pgK1 = Kp + (size_t)(b*8+h0+1) * 2048 * 64 + (size_t)srow * 64   + scu * 8;
    const unsigned short* pgV0 = Vt + (size_t)(b*8+h0  ) * 64 * 2048 + (size_t)srow * 2048 + scu * 8;
    const unsigned short* pgV1 = Vt + (size_t)(b*8+h0+1) * 64 * 2048 + (size_t)srow * 2048 + scu * 8;
    const float* pm = mask + ((size_t)b * 2048 + qg) * 2048 + hi * 4;

    uint4 ka0, kc0, ka1, kc1, va0, vc0, va1, vc1;
    float4 mA[2][4], mB[2][4];

    // prologue: tile 0 -> LDS[0], mask tile 0 -> mA
    LOADNEXT(mA);
    STORE(0);
    __syncthreads();

    for (int kb2 = 0; kb2 < 16; ++kb2) {
        // even half: compute LDS[0]/mA, prefetch -> LDS[1]/mB
        {
            LOADNEXT(mB);
            COMPUTE(lK0c, lV0c, mA);
            STORE(1);
            __syncthreads();
        }
        // odd half: compute LDS[1]/mB, prefetch -> LDS[0]/mA
        {
            if (kb2 < 15) LOADNEXT(mA);
            COMPUTE(lK1c, lV1c, mB);
            if (kb2 < 15) {
                STORE(0);
                __syncthreads();
            }
        }
    }

    // final l reduction: halves (lane, lane^32) hold disjoint k partials
    lsum += __shfl_xor(lsum, 32);
    const float inv = 1.0f / lsum;

    // epilogue: O^T col=q, row(d) = (reg&3)+8*(reg>>2)+4*hi (+32 for o1)
    unsigned short* ao = AO + ((size_t)qg * 4 + b) * 512 + (h0 + hw) * 64;
#pragma unroll
    for (int g = 0; g < 4; ++g) {
        const int d0 = g * 8 + hi * 4;
        *(uint2*)(ao + d0) =
            make_uint2(pk2(o0[4*g+0] * inv, o0[4*g+1] * inv),
                       pk2(o0[4*g+2] * inv, o0[4*g+3] * inv));
        *(uint2*)(ao + 32 + d0) =
            make_uint2(pk2(o1[4*g+0] * inv, o1[4*g+1] * inv),
                       pk2(o1[4*g+2] * inv, o1[4*g+3] * inv));
    }
}

// ---------------------------------------------------------------------------
// Kernel 2: output projection. out = AO(bf16) @ W_out^T + b_out (fp32 out).
// ---------------------------------------------------------------------------
__global__ __launch_bounds__(256) void oproj_kernel(
    const unsigned short* __restrict__ A, const float* __restrict__ W,
    const float* __restrict__ bias, float* __restrict__ out)
{
    __shared__ unsigned short lA[128][40];
    __shared__ unsigned short lB[128][40];

    const int rb = blockIdx.y * 128;
    const int nb = blockIdx.x * 128;
    const int tid  = threadIdx.x;
    const int lane = tid & 63, wave = tid >> 6;
    const int wr = wave >> 1, wc = wave & 1;
    const int lq = lane & 15, lg = lane >> 4;

    f32x4 acc[4][4];
#pragma unroll
    for (int i = 0; i < 4; ++i)
#pragma unroll
        for (int j = 0; j < 4; ++j) acc[i][j] = (f32x4){0.f, 0.f, 0.f, 0.f};

    const int srow = tid >> 1;
    const int scol = (tid & 1) * 16;

    for (int kt = 0; kt < 16; ++kt) {
        const int k0 = kt * 32;
        if (kt) __syncthreads();
        {   // A tile (bf16 passthrough)
            const unsigned short* g = A + (size_t)(rb + srow) * 512 + k0 + scol;
            *(uint4*)&lA[srow][scol]     = *(const uint4*)g;
            *(uint4*)&lA[srow][scol + 8] = *(const uint4*)(g + 8);
        }
        {   // B tile (weights fp32 -> bf16)
            const float* g = W + (size_t)(nb + srow) * 512 + k0 + scol;
            float4 x0 = *(const float4*)(g + 0);
            float4 x1 = *(const float4*)(g + 4);
            float4 x2 = *(const float4*)(g + 8);
            float4 x3 = *(const float4*)(g + 12);
            uint4 w0, w1;
            w0.x = pk2(x0.x, x0.y); w0.y = pk2(x0.z, x0.w);
            w0.z = pk2(x1.x, x1.y); w0.w = pk2(x1.z, x1.w);
            w1.x = pk2(x2.x, x2.y); w1.y = pk2(x2.z, x2.w);
            w1.z = pk2(x3.x, x3.y); w1.w = pk2(x3.z, x3.w);
            *(uint4*)&lB[srow][scol] = w0;
            *(uint4*)&lB[srow][scol + 8] = w1;
        }
        __syncthreads();

        bf16x8 af[4], bfr[4];
#pragma unroll
        for (int mi = 0; mi < 4; ++mi)
            af[mi] = *(const bf16x8*)&lA[wr * 64 + mi * 16 + lq][lg * 8];
#pragma unroll
        for (int ni = 0; ni < 4; ++ni)
            bfr[ni] = *(const bf16x8*)&lB[wc * 64 + ni * 16 + lq][lg * 8];
#pragma unroll
        for (int mi = 0; mi < 4; ++mi)
#pragma unroll
            for (int ni = 0; ni < 4; ++ni)
                acc[mi][ni] = __builtin_amdgcn_mfma_f32_16x16x32_bf16(
                    af[mi], bfr[ni], acc[mi][ni], 0, 0, 0);
    }

#pragma unroll
    for (int ni = 0; ni < 4; ++ni) {
        const int n = nb + wc * 64 + ni * 16 + lq;
        const float bv = bias[n];
#pragma unroll
        for (int mi = 0; mi < 4; ++mi) {
#pragma unroll
            for (int r = 0; r < 4; ++r) {
                const int t = rb + wr * 64 + mi * 16 + lg * 4 + r;
                out[(size_t)t * 512 + n] = acc[mi][ni][r] + bv;
            }
        }
    }
}

extern "C" void kernel_launch(void* const* d_in, const int* in_sizes, int n_in,
                              void* d_out, int out_size, void* d_ws, size_t ws_size,
                              hipStream_t stream)
{
    (void)in_sizes; (void)n_in; (void)out_size; (void)ws_size;
    const float* query = (const float*)d_in[0];
    const float* key   = (const float*)d_in[1];
    const float* value = (const float*)d_in[2];
    const float* mask  = (const float*)d_in[3];
    const float* w_in  = (const float*)d_in[4];
    const float* b_in  = (const float*)d_in[5];
    const float* w_out = (const float*)d_in[6];
    const float* b_out = (const float*)d_in[7];
    float* out = (float*)d_out;

    char* ws = (char*)d_ws;
    unsigned short* Qp = (unsigned short*)(ws);                            // [32][2048][64]
    unsigned short* Kp = (unsigned short*)(ws + (size_t)8 * 1024 * 1024);  // [32][2048][64]
    unsigned short* Vt = (unsigned short*)(ws + (size_t)16 * 1024 * 1024); // [32][64][2048]
    unsigned short* AO = (unsigned short*)(ws + (size_t)24 * 1024 * 1024); // [8192][512]

    qkv_kernel<<<dim3(4, 64, 3), 256, 0, stream>>>(query, key, value, w_in, b_in,
                                                   Qp, Kp, Vt);
    attn_kernel<<<dim3(512), 256, 0, stream>>>(Qp, Kp, Vt, mask, AO);
    oproj_kernel<<<dim3(4, 64), 256, 0, stream>>>(AO, w_out, b_out, out);
}

// Round 8
// 159.136 us; speedup vs baseline: 1.0660x; 1.0660x over previous
//
#include <hip/hip_runtime.h>

// MHA forward: S=2048, B=4, E=512, H=8, D=64.
// qkv_kernel -> maskprep_kernel -> attn_kernel -> oproj_kernel.
// R8: the invariant ~110us was the mask FRAGMENT GATHER in attn (each lane's
// 16B from its own q-row = 64-line gather per instr, ~4k TA-cycles/CU/iter).
// maskprep pays that gather ONCE: emits bf16 fragment-layout
// Mf[b][qt32][kt32][lane][16] (L2E folded), so attn's mask read is
// wave-uniform base + lane*32B -> fully coalesced. Attn core stays R5:
// 32x32x16 MFMA, swapped QK^T, in-register P (cvt_pk + permlane32_swap),
// fixed-reference softmax, dbuf K/V LDS (XOR swizzle), 1 barrier/tile.

#define L2E 1.44269504088896340736f

typedef __attribute__((ext_vector_type(8))) __bf16 bf16x8;
typedef __attribute__((ext_vector_type(4))) float f32x4;
typedef __attribute__((ext_vector_type(16))) float f32x16;

// packed bf16 pair via native casts (compiler emits v_cvt_pk_bf16_f32)
static __device__ __forceinline__ unsigned pk2(float a, float b) {
    union { unsigned u; __bf16 h[2]; } cv;
    cv.h[0] = (__bf16)a; cv.h[1] = (__bf16)b;
    return cv.u;
}

static __device__ __forceinline__ unsigned short f2bf(float f) {
    union { unsigned short s; __bf16 h; } cv;
    cv.h = (__bf16)f;
    return cv.s;
}

static __device__ __forceinline__ float bflo(unsigned u) {
    union { unsigned u; float f; } cv; cv.u = u << 16; return cv.f;
}
static __device__ __forceinline__ float bfhi(unsigned u) {
    union { unsigned u; float f; } cv; cv.u = u & 0xFFFF0000u; return cv.f;
}

// ---------------------------------------------------------------------------
// Kernel 0: QKV projection. z selects (input, weight slice, dst).
//   z=0 -> Qp[bh][s][d] scaled by L2E/8 (folds softmax log2e), z=1 -> Kp,
//   z=2 -> Vt[bh][d][s] (transposed for PV A-operand).
// ---------------------------------------------------------------------------
__global__ __launch_bounds__(256) void qkv_kernel(
    const float* __restrict__ Xq, const float* __restrict__ Xk,
    const float* __restrict__ Xv, const float* __restrict__ W,
    const float* __restrict__ bias,
    unsigned short* __restrict__ Qp, unsigned short* __restrict__ Kp,
    unsigned short* __restrict__ Vt)
{
    __shared__ unsigned short lA[128][40];  // pad 32->40 shorts
    __shared__ unsigned short lB[128][40];

    const int z = blockIdx.z;
    const float* X  = (z == 0) ? Xq : (z == 1) ? Xk : Xv;
    const float* Wz = W + (size_t)z * 512 * 512;
    const int rb = blockIdx.y * 128;
    const int nb = blockIdx.x * 128;
    const int tid  = threadIdx.x;
    const int lane = tid & 63, wave = tid >> 6;
    const int wr = wave >> 1, wc = wave & 1;
    const int lq = lane & 15, lg = lane >> 4;

    f32x4 acc[4][4];
#pragma unroll
    for (int i = 0; i < 4; ++i)
#pragma unroll
        for (int j = 0; j < 4; ++j) acc[i][j] = (f32x4){0.f, 0.f, 0.f, 0.f};

    const int srow = tid >> 1;          // 0..127
    const int scol = (tid & 1) * 16;    // 0 or 16 (elements)

    for (int kt = 0; kt < 16; ++kt) {
        const int k0 = kt * 32;
        if (kt) __syncthreads();
        {   // A tile (fp32 -> bf16)
            const float* g = X + (size_t)(rb + srow) * 512 + k0 + scol;
            float4 x0 = *(const float4*)(g + 0);
            float4 x1 = *(const float4*)(g + 4);
            float4 x2 = *(const float4*)(g + 8);
            float4 x3 = *(const float4*)(g + 12);
            uint4 w0, w1;
            w0.x = pk2(x0.x, x0.y); w0.y = pk2(x0.z, x0.w);
            w0.z = pk2(x1.x, x1.y); w0.w = pk2(x1.z, x1.w);
            w1.x = pk2(x2.x, x2.y); w1.y = pk2(x2.z, x2.w);
            w1.z = pk2(x3.x, x3.y); w1.w = pk2(x3.z, x3.w);
            *(uint4*)&lA[srow][scol] = w0;
            *(uint4*)&lA[srow][scol + 8] = w1;
        }
        {   // B tile (weights fp32 -> bf16); W is [n][k], k contiguous
            const float* g = Wz + (size_t)(nb + srow) * 512 + k0 + scol;
            float4 x0 = *(const float4*)(g + 0);
            float4 x1 = *(const float4*)(g + 4);
            float4 x2 = *(const float4*)(g + 8);
            float4 x3 = *(const float4*)(g + 12);
            uint4 w0, w1;
            w0.x = pk2(x0.x, x0.y); w0.y = pk2(x0.z, x0.w);
            w0.z = pk2(x1.x, x1.y); w0.w = pk2(x1.z, x1.w);
            w1.x = pk2(x2.x, x2.y); w1.y = pk2(x2.z, x2.w);
            w1.z = pk2(x3.x, x3.y); w1.w = pk2(x3.z, x3.w);
            *(uint4*)&lB[srow][scol] = w0;
            *(uint4*)&lB[srow][scol + 8] = w1;
        }
        __syncthreads();

        bf16x8 af[4], bf[4];
#pragma unroll
        for (int mi = 0; mi < 4; ++mi)
            af[mi] = *(const bf16x8*)&lA[wr * 64 + mi * 16 + lq][lg * 8];
#pragma unroll
        for (int ni = 0; ni < 4; ++ni)
            bf[ni] = *(const bf16x8*)&lB[wc * 64 + ni * 16 + lq][lg * 8];
#pragma unroll
        for (int mi = 0; mi < 4; ++mi)
#pragma unroll
            for (int ni = 0; ni < 4; ++ni)
                acc[mi][ni] = __builtin_amdgcn_mfma_f32_16x16x32_bf16(
                    af[mi], bf[ni], acc[mi][ni], 0, 0, 0);
    }

    // epilogue: C layout col = lane&15 (n), row = (lane>>4)*4 + r (m)
    const float* bz = bias + z * 512;
#pragma unroll
    for (int ni = 0; ni < 4; ++ni) {
        const int n = nb + wc * 64 + ni * 16 + lq;
        const float bv = bz[n];
        const int h = n >> 6, d = n & 63;
#pragma unroll
        for (int mi = 0; mi < 4; ++mi) {
#pragma unroll
            for (int r = 0; r < 4; ++r) {
                const int t = rb + wr * 64 + mi * 16 + lg * 4 + r;
                float v = acc[mi][ni][r] + bv;
                const int s = t >> 2, b = t & 3;
                if (z == 0) {
                    v *= 0.125f * L2E;  // 1/sqrt(D) * log2(e)
                    Qp[((size_t)(b * 8 + h) * 2048 + s) * 64 + d] = f2bf(v);
                } else if (z == 1) {
                    Kp[((size_t)(b * 8 + h) * 2048 + s) * 64 + d] = f2bf(v);
                } else {
                    Vt[((size_t)(b * 8 + h) * 64 + d) * 2048 + s] = f2bf(v);
                }
            }
        }
    }
}

// ---------------------------------------------------------------------------
// Kernel 0.5: mask -> bf16 fragment layout (gather paid ONCE).
// Mf[((b*64+qt)*64+kt)*1024 + lane*16 + jj] = bf16(mask[b][qt*32+(lane&31)]
//     [kt*32 + (jj&3) + 8*(jj>>2) + 4*(lane>>5)] * L2E)
// so attn's C-init for a 32x32 sub-tile is a coalesced lane*32B read.
// grid (4, 256): y = b*64+qt, x = ktg; wave w covers kt = ktg*16+w*4 .. +3.
// ---------------------------------------------------------------------------
__global__ __launch_bounds__(256) void maskprep_kernel(
    const float* __restrict__ mask, unsigned short* __restrict__ Mf)
{
    const int tid  = threadIdx.x;
    const int lane = tid & 63, wave = tid >> 6;
    const int lc = lane & 31, hi = lane >> 5;
    const int bq = blockIdx.y;                 // b*64 + qt
    const float* row = mask + ((size_t)(bq >> 6) * 2048 + (bq & 63) * 32 + lc) * 2048;

#pragma unroll
    for (int i = 0; i < 4; ++i) {
        const int kt = blockIdx.x * 16 + wave * 4 + i;
        unsigned short* dst = Mf + ((size_t)bq * 64 + kt) * 1024 + lane * 16;
        uint2 ow[4];
#pragma unroll
        for (int g = 0; g < 4; ++g) {
            float4 v = *(const float4*)(row + kt * 32 + g * 8 + hi * 4);
            ow[g] = make_uint2(pk2(v.x * L2E, v.y * L2E),
                               pk2(v.z * L2E, v.w * L2E));
        }
        *(uint4*)(dst)     = make_uint4(ow[0].x, ow[0].y, ow[1].x, ow[1].y);
        *(uint4*)(dst + 8) = make_uint4(ow[2].x, ow[2].y, ow[3].x, ow[3].y);
    }
}

// ---------------------------------------------------------------------------
// Kernel 1: flash attention, 32x32x16 MFMA, swapped QK^T.
// grid = (16 q-tiles of 128, 32 bh); 4 waves x 32 q-rows.
// Mask C-init from Mf (coalesced, bf16, L2E-folded; unpack = shift/and).
// K/V dbuf LDS (XOR swizzle), 1 barrier/tile, reg prefetch, kb-loop x2.
// ---------------------------------------------------------------------------
#define SWAP32(a, b) asm("v_permlane32_swap_b32 %0, %1" : "+v"(a), "+v"(b))

#define COMPUTE(KC, VC, M) do {                                                \
    bf16x8 pf[4];                                                              \
    _Pragma("unroll")                                                          \
    for (int kblk = 0; kblk < 2; ++kblk) {                                     \
        f32x16 z;                                                              \
        {                                                                      \
            const uint4 m0 = M[kblk][0], m1 = M[kblk][1];                      \
            z[0]  = bflo(m0.x); z[1]  = bfhi(m0.x);                            \
            z[2]  = bflo(m0.y); z[3]  = bfhi(m0.y);                            \
            z[4]  = bflo(m0.z); z[5]  = bfhi(m0.z);                            \
            z[6]  = bflo(m0.w); z[7]  = bfhi(m0.w);                            \
            z[8]  = bflo(m1.x); z[9]  = bfhi(m1.x);                            \
            z[10] = bflo(m1.y); z[11] = bfhi(m1.y);                            \
            z[12] = bflo(m1.z); z[13] = bfhi(m1.z);                            \
            z[14] = bflo(m1.w); z[15] = bfhi(m1.w);                            \
        }                                                                      \
        __builtin_amdgcn_s_setprio(1);                                         \
        _Pragma("unroll")                                                      \
        for (int s = 0; s < 4; ++s) {                                          \
            bf16x8 kf = *(const bf16x8*)((KC) + fof[kblk][s]);                 \
            z = __builtin_amdgcn_mfma_f32_32x32x16_bf16(kf, qf[s], z, 0,0,0);  \
        }                                                                      \
        __builtin_amdgcn_s_setprio(0);                                         \
        float p[16];                                                           \
        _Pragma("unroll")                                                      \
        for (int i = 0; i < 16; ++i) p[i] = exp2f(z[i]);                       \
        lsum += (((p[0]+p[1])+(p[2]+p[3])) + ((p[4]+p[5])+(p[6]+p[7])))        \
              + (((p[8]+p[9])+(p[10]+p[11])) + ((p[12]+p[13])+(p[14]+p[15]))); \
        unsigned a0 = pk2(p[0], p[1]),   b0 = pk2(p[4], p[5]);                 \
        unsigned a1 = pk2(p[2], p[3]),   b1 = pk2(p[6], p[7]);                 \
        SWAP32(a0, b0); SWAP32(a1, b1);                                        \
        union { unsigned w[4]; bf16x8 v; } u0;                                 \
        u0.w[0] = a0; u0.w[1] = a1; u0.w[2] = b0; u0.w[3] = b1;                \
        pf[kblk*2] = u0.v;                                                     \
        unsigned c0 = pk2(p[8], p[9]),   d0 = pk2(p[12], p[13]);               \
        unsigned c1 = pk2(p[10], p[11]), d1 = pk2(p[14], p[15]);               \
        SWAP32(c0, d0); SWAP32(c1, d1);                                        \
        union { unsigned w[4]; bf16x8 v; } u1;                                 \
        u1.w[0] = c0; u1.w[1] = c1; u1.w[2] = d0; u1.w[3] = d1;                \
        pf[kblk*2+1] = u1.v;                                                   \
    }                                                                          \
    __builtin_amdgcn_s_setprio(1);                                             \
    _Pragma("unroll")                                                          \
    for (int s = 0; s < 4; ++s) {                                              \
        bf16x8 vf0 = *(const bf16x8*)((VC) + fof[0][s]);                       \
        o0 = __builtin_amdgcn_mfma_f32_32x32x16_bf16(vf0, pf[s], o0, 0,0,0);   \
        bf16x8 vf1 = *(const bf16x8*)((VC) + fof[1][s]);                       \
        o1 = __builtin_amdgcn_mfma_f32_32x32x16_bf16(vf1, pf[s], o1, 0,0,0);   \
    }                                                                          \
    __builtin_amdgcn_s_setprio(0);                                             \
} while (0)

#define LOADNEXT(MD) do {                                                      \
    ka = *(const uint4*)(pgK); kc = *(const uint4*)(pgK + 8);                  \
    va = *(const uint4*)(pgV); vc = *(const uint4*)(pgV + 8);                  \
    MD[0][0] = *(const uint4*)(pmf);                                           \
    MD[0][1] = *(const uint4*)(pmf + 8);                                       \
    MD[1][0] = *(const uint4*)(pmf + 1024);                                    \
    MD[1][1] = *(const uint4*)(pmf + 1032);                                    \
    pgK += 4096; pgV += 64; pmf += 2048;                                       \
} while (0)

#define STORE(BUF) do {                                                        \
    *(uint4*)&lK[BUF][srow][su0 * 8] = ka;                                     \
    *(uint4*)&lK[BUF][srow][su1 * 8] = kc;                                     \
    *(uint4*)&lV[BUF][srow][su0 * 8] = va;                                     \
    *(uint4*)&lV[BUF][srow][su1 * 8] = vc;                                     \
} while (0)

__global__ __launch_bounds__(256, 2) void attn_kernel(
    const unsigned short* __restrict__ Qp, const unsigned short* __restrict__ Kp,
    const unsigned short* __restrict__ Vt, const unsigned short* __restrict__ Mf,
    unsigned short* __restrict__ AO)
{
    __shared__ unsigned short lK[2][64][64];   // [buf][k][d], swizzled 16B units
    __shared__ unsigned short lV[2][64][64];   // [buf][d][k], same swizzle

    const int bh = blockIdx.y;
    const int b = bh >> 3, h = bh & 7;
    const int qb = blockIdx.x * 128;
    const int tid  = threadIdx.x;
    const int lane = tid & 63, wave = tid >> 6;
    const int lc = lane & 31, hi = lane >> 5;
    const int qg = qb + wave * 32 + lc;

    // Q B-fragments: lane needs Q[qg][s*16 + hi*8 + 0..7]
    bf16x8 qf[4];
    {
        const unsigned short* qp = Qp + ((size_t)bh * 2048 + qg) * 64 + hi * 8;
#pragma unroll
        for (int s = 0; s < 4; ++s)
            qf[s] = *(const bf16x8*)(qp + s * 16);
    }

    f32x16 o0, o1;
#pragma unroll
    for (int i = 0; i < 16; ++i) { o0[i] = 0.f; o1[i] = 0.f; }
    float lsum = 0.f;

    // K/V fragment byte-offsets in a [64][64]-short tile:
    // row = blk*32 + lc; 16B-unit = (2s|hi) ^ (row&7)
    int fof[2][4];
#pragma unroll
    for (int blk = 0; blk < 2; ++blk)
#pragma unroll
        for (int s = 0; s < 4; ++s)
            fof[blk][s] = (blk * 32 + lc) * 128 +
                          ((((s << 1) | hi) ^ (lane & 7)) * 16);

    const char* lK0c = (const char*)&lK[0][0][0];
    const char* lK1c = (const char*)&lK[1][0][0];
    const char* lV0c = (const char*)&lV[0][0][0];
    const char* lV1c = (const char*)&lV[1][0][0];

    // staging: thread owns row tid>>2, 16B-units (tid&3)*2 and +1, XOR swizzle
    const int srow = tid >> 2;
    const int scu  = (tid & 3) * 2;
    const int su0  = (scu    ) ^ (srow & 7);
    const int su1  = (scu + 1) ^ (srow & 7);
    const unsigned short* pgK = Kp + (size_t)bh * 2048 * 64 + (size_t)srow * 64 + scu * 8;
    const unsigned short* pgV = Vt + (size_t)bh * 64 * 2048 + (size_t)srow * 2048 + scu * 8;
    // mask fragments: wave-uniform tile base + lane*16 shorts (coalesced)
    const unsigned short* pmf = Mf +
        ((size_t)(b * 64 + (qb >> 5) + wave) * 64) * 1024 + lane * 16;

    uint4 ka, kc, va, vc;
    uint4 mA[2][2], mB[2][2];

    // prologue: tile 0 -> LDS[0], mask tile 0 -> mA
    LOADNEXT(mA);
    STORE(0);
    __syncthreads();

    for (int kb2 = 0; kb2 < 16; ++kb2) {
        // even half: compute LDS[0]/mA, prefetch -> LDS[1]/mB
        {
            LOADNEXT(mB);
            COMPUTE(lK0c, lV0c, mA);
            STORE(1);
            __syncthreads();
        }
        // odd half: compute LDS[1]/mB, prefetch -> LDS[0]/mA
        {
            if (kb2 < 15) LOADNEXT(mA);
            COMPUTE(lK1c, lV1c, mB);
            if (kb2 < 15) {
                STORE(0);
                __syncthreads();
            }
        }
    }

    // final l reduction: halves (lane, lane^32) hold disjoint k partials
    lsum += __shfl_xor(lsum, 32);
    const float inv = 1.0f / lsum;

    // epilogue: O^T col=q, row(d) = (reg&3)+8*(reg>>2)+4*hi (+32 for o1)
    unsigned short* ao = AO + ((size_t)qg * 4 + b) * 512 + h * 64;
#pragma unroll
    for (int g = 0; g < 4; ++g) {
        const int d0 = g * 8 + hi * 4;
        *(uint2*)(ao + d0) =
            make_uint2(pk2(o0[4*g+0] * inv, o0[4*g+1] * inv),
                       pk2(o0[4*g+2] * inv, o0[4*g+3] * inv));
        *(uint2*)(ao + 32 + d0) =
            make_uint2(pk2(o1[4*g+0] * inv, o1[4*g+1] * inv),
                       pk2(o1[4*g+2] * inv, o1[4*g+3] * inv));
    }
}

// ---------------------------------------------------------------------------
// Kernel 2: output projection. out = AO(bf16) @ W_out^T + b_out (fp32 out).
// ---------------------------------------------------------------------------
__global__ __launch_bounds__(256) void oproj_kernel(
    const unsigned short* __restrict__ A, const float* __restrict__ W,
    const float* __restrict__ bias, float* __restrict__ out)
{
    __shared__ unsigned short lA[128][40];
    __shared__ unsigned short lB[128][40];

    const int rb = blockIdx.y * 128;
    const int nb = blockIdx.x * 128;
    const int tid  = threadIdx.x;
    const int lane = tid & 63, wave = tid >> 6;
    const int wr = wave >> 1, wc = wave & 1;
    const int lq = lane & 15, lg = lane >> 4;

    f32x4 acc[4][4];
#pragma unroll
    for (int i = 0; i < 4; ++i)
#pragma unroll
        for (int j = 0; j < 4; ++j) acc[i][j] = (f32x4){0.f, 0.f, 0.f, 0.f};

    const int srow = tid >> 1;
    const int scol = (tid & 1) * 16;

    for (int kt = 0; kt < 16; ++kt) {
        const int k0 = kt * 32;
        if (kt) __syncthreads();
        {   // A tile (bf16 passthrough)
            const unsigned short* g = A + (size_t)(rb + srow) * 512 + k0 + scol;
            *(uint4*)&lA[srow][scol]     = *(const uint4*)g;
            *(uint4*)&lA[srow][scol + 8] = *(const uint4*)(g + 8);
        }
        {   // B tile (weights fp32 -> bf16)
            const float* g = W + (size_t)(nb + srow) * 512 + k0 + scol;
            float4 x0 = *(const float4*)(g + 0);
            float4 x1 = *(const float4*)(g + 4);
            float4 x2 = *(const float4*)(g + 8);
            float4 x3 = *(const float4*)(g + 12);
            uint4 w0, w1;
            w0.x = pk2(x0.x, x0.y); w0.y = pk2(x0.z, x0.w);
            w0.z = pk2(x1.x, x1.y); w0.w = pk2(x1.z, x1.w);
            w1.x = pk2(x2.x, x2.y); w1.y = pk2(x2.z, x2.w);
            w1.z = pk2(x3.x, x3.y); w1.w = pk2(x3.z, x3.w);
            *(uint4*)&lB[srow][scol] = w0;
            *(uint4*)&lB[srow][scol + 8] = w1;
        }
        __syncthreads();

        bf16x8 af[4], bfr[4];
#pragma unroll
        for (int mi = 0; mi < 4; ++mi)
            af[mi] = *(const bf16x8*)&lA[wr * 64 + mi * 16 + lq][lg * 8];
#pragma unroll
        for (int ni = 0; ni < 4; ++ni)
            bfr[ni] = *(const bf16x8*)&lB[wc * 64 + ni * 16 + lq][lg * 8];
#pragma unroll
        for (int mi = 0; mi < 4; ++mi)
#pragma unroll
            for (int ni = 0; ni < 4; ++ni)
                acc[mi][ni] = __builtin_amdgcn_mfma_f32_16x16x32_bf16(
                    af[mi], bfr[ni], acc[mi][ni], 0, 0, 0);
    }

#pragma unroll
    for (int ni = 0; ni < 4; ++ni) {
        const int n = nb + wc * 64 + ni * 16 + lq;
        const float bv = bias[n];
#pragma unroll
        for (int mi = 0; mi < 4; ++mi) {
#pragma unroll
            for (int r = 0; r < 4; ++r) {
                const int t = rb + wr * 64 + mi * 16 + lg * 4 + r;
                out[(size_t)t * 512 + n] = acc[mi][ni][r] + bv;
            }
        }
    }
}

extern "C" void kernel_launch(void* const* d_in, const int* in_sizes, int n_in,
                              void* d_out, int out_size, void* d_ws, size_t ws_size,
                              hipStream_t stream)
{
    (void)in_sizes; (void)n_in; (void)out_size; (void)ws_size;
    const float* query = (const float*)d_in[0];
    const float* key   = (const float*)d_in[1];
    const float* value = (const float*)d_in[2];
    const float* mask  = (const float*)d_in[3];
    const float* w_in  = (const float*)d_in[4];
    const float* b_in  = (const float*)d_in[5];
    const float* w_out = (const float*)d_in[6];
    const float* b_out = (const float*)d_in[7];
    float* out = (float*)d_out;

    char* ws = (char*)d_ws;
    unsigned short* Qp = (unsigned short*)(ws);                            // [32][2048][64]
    unsigned short* Kp = (unsigned short*)(ws + (size_t)8 * 1024 * 1024);  // [32][2048][64]
    unsigned short* Vt = (unsigned short*)(ws + (size_t)16 * 1024 * 1024); // [32][64][2048]
    unsigned short* AO = (unsigned short*)(ws + (size_t)24 * 1024 * 1024); // [8192][512]
    unsigned short* Mf = (unsigned short*)(ws + (size_t)32 * 1024 * 1024); // [4][64][64][64][16]

    qkv_kernel<<<dim3(4, 64, 3), 256, 0, stream>>>(query, key, value, w_in, b_in,
                                                   Qp, Kp, Vt);
    maskprep_kernel<<<dim3(4, 256), 256, 0, stream>>>(mask, Mf);
    attn_kernel<<<dim3(16, 32), 256, 0, stream>>>(Qp, Kp, Vt, Mf, AO);
    oproj_kernel<<<dim3(4, 64), 256, 0, stream>>>(AO, w_out, b_out, out);
}

// Round 12
// 154.207 us; speedup vs baseline: 1.1001x; 1.0320x over previous
//
#include <hip/hip_runtime.h>

// MHA forward: S=2048, B=4, E=512, H=8, D=64.
// qkv_kernel -> maskprep_kernel -> attn_kernel -> oproj_kernel.
// R12 = R8 (last PASS, attn byte-identical incl. exp2f + native pk2) with
// ONLY the LDS-transpose maskprep swapped in (verified index-identical
// output to R8's gather maskprep).
// LESSON (R9-R11): inline-asm v_exp_f32 is poison — it's a VALU trans op
// whose mandatory wait-states the compiler cannot insert around an asm
// string. exp2f lowers to the same instruction WITH hazard handling.

#define L2E 1.44269504088896340736f

typedef __attribute__((ext_vector_type(8))) __bf16 bf16x8;
typedef __attribute__((ext_vector_type(4))) float f32x4;
typedef __attribute__((ext_vector_type(16))) float f32x16;

// packed bf16 pair via native casts (compiler emits v_cvt_pk_bf16_f32)
static __device__ __forceinline__ unsigned pk2(float a, float b) {
    union { unsigned u; __bf16 h[2]; } cv;
    cv.h[0] = (__bf16)a; cv.h[1] = (__bf16)b;
    return cv.u;
}

static __device__ __forceinline__ unsigned short f2bf(float f) {
    union { unsigned short s; __bf16 h; } cv;
    cv.h = (__bf16)f;
    return cv.s;
}

static __device__ __forceinline__ float bflo(unsigned u) {
    union { unsigned u; float f; } cv; cv.u = u << 16; return cv.f;
}
static __device__ __forceinline__ float bfhi(unsigned u) {
    union { unsigned u; float f; } cv; cv.u = u & 0xFFFF0000u; return cv.f;
}

// ---------------------------------------------------------------------------
// Kernel 0: QKV projection. z selects (input, weight slice, dst).
//   z=0 -> Qp[bh][s][d] scaled by L2E/8, z=1 -> Kp, z=2 -> Vt[bh][d][s].
// ---------------------------------------------------------------------------
__global__ __launch_bounds__(256) void qkv_kernel(
    const float* __restrict__ Xq, const float* __restrict__ Xk,
    const float* __restrict__ Xv, const float* __restrict__ W,
    const float* __restrict__ bias,
    unsigned short* __restrict__ Qp, unsigned short* __restrict__ Kp,
    unsigned short* __restrict__ Vt)
{
    __shared__ unsigned short lA[128][40];
    __shared__ unsigned short lB[128][40];

    const int z = blockIdx.z;
    const float* X  = (z == 0) ? Xq : (z == 1) ? Xk : Xv;
    const float* Wz = W + (size_t)z * 512 * 512;
    const int rb = blockIdx.y * 128;
    const int nb = blockIdx.x * 128;
    const int tid  = threadIdx.x;
    const int lane = tid & 63, wave = tid >> 6;
    const int wr = wave >> 1, wc = wave & 1;
    const int lq = lane & 15, lg = lane >> 4;

    f32x4 acc[4][4];
#pragma unroll
    for (int i = 0; i < 4; ++i)
#pragma unroll
        for (int j = 0; j < 4; ++j) acc[i][j] = (f32x4){0.f, 0.f, 0.f, 0.f};

    const int srow = tid >> 1;
    const int scol = (tid & 1) * 16;

    for (int kt = 0; kt < 16; ++kt) {
        const int k0 = kt * 32;
        if (kt) __syncthreads();
        {
            const float* g = X + (size_t)(rb + srow) * 512 + k0 + scol;
            float4 x0 = *(const float4*)(g + 0);
            float4 x1 = *(const float4*)(g + 4);
            float4 x2 = *(const float4*)(g + 8);
            float4 x3 = *(const float4*)(g + 12);
            uint4 w0, w1;
            w0.x = pk2(x0.x, x0.y); w0.y = pk2(x0.z, x0.w);
            w0.z = pk2(x1.x, x1.y); w0.w = pk2(x1.z, x1.w);
            w1.x = pk2(x2.x, x2.y); w1.y = pk2(x2.z, x2.w);
            w1.z = pk2(x3.x, x3.y); w1.w = pk2(x3.z, x3.w);
            *(uint4*)&lA[srow][scol] = w0;
            *(uint4*)&lA[srow][scol + 8] = w1;
        }
        {
            const float* g = Wz + (size_t)(nb + srow) * 512 + k0 + scol;
            float4 x0 = *(const float4*)(g + 0);
            float4 x1 = *(const float4*)(g + 4);
            float4 x2 = *(const float4*)(g + 8);
            float4 x3 = *(const float4*)(g + 12);
            uint4 w0, w1;
            w0.x = pk2(x0.x, x0.y); w0.y = pk2(x0.z, x0.w);
            w0.z = pk2(x1.x, x1.y); w0.w = pk2(x1.z, x1.w);
            w1.x = pk2(x2.x, x2.y); w1.y = pk2(x2.z, x2.w);
            w1.z = pk2(x3.x, x3.y); w1.w = pk2(x3.z, x3.w);
            *(uint4*)&lB[srow][scol] = w0;
            *(uint4*)&lB[srow][scol + 8] = w1;
        }
        __syncthreads();

        bf16x8 af[4], bf[4];
#pragma unroll
        for (int mi = 0; mi < 4; ++mi)
            af[mi] = *(const bf16x8*)&lA[wr * 64 + mi * 16 + lq][lg * 8];
#pragma unroll
        for (int ni = 0; ni < 4; ++ni)
            bf[ni] = *(const bf16x8*)&lB[wc * 64 + ni * 16 + lq][lg * 8];
#pragma unroll
        for (int mi = 0; mi < 4; ++mi)
#pragma unroll
            for (int ni = 0; ni < 4; ++ni)
                acc[mi][ni] = __builtin_amdgcn_mfma_f32_16x16x32_bf16(
                    af[mi], bf[ni], acc[mi][ni], 0, 0, 0);
    }

    const float* bz = bias + z * 512;
#pragma unroll
    for (int ni = 0; ni < 4; ++ni) {
        const int n = nb + wc * 64 + ni * 16 + lq;
        const float bv = bz[n];
        const int h = n >> 6, d = n & 63;
#pragma unroll
        for (int mi = 0; mi < 4; ++mi) {
#pragma unroll
            for (int r = 0; r < 4; ++r) {
                const int t = rb + wr * 64 + mi * 16 + lg * 4 + r;
                float v = acc[mi][ni][r] + bv;
                const int s = t >> 2, b = t & 3;
                if (z == 0) {
                    v *= 0.125f * L2E;
                    Qp[((size_t)(b * 8 + h) * 2048 + s) * 64 + d] = f2bf(v);
                } else if (z == 1) {
                    Kp[((size_t)(b * 8 + h) * 2048 + s) * 64 + d] = f2bf(v);
                } else {
                    Vt[((size_t)(b * 8 + h) * 64 + d) * 2048 + s] = f2bf(v);
                }
            }
        }
    }
}

// ---------------------------------------------------------------------------
// Kernel 0.5: mask -> bf16 fragment layout via LDS transpose (coalesced).
// grid (8 k-chunks of 256, 256 bq); 256 threads.
// Read phase: 32 q-rows x 256 k fp32, contiguous 128B per 8-lane group.
// Write phase: Mf[(bq*64+kt)*1024 + lane*16 + jj] =
//   mask[b][qt*32+(lane&31)][kt*32 + (jj&3)+8*(jj>>2)+4*(lane>>5)] * L2E
// (identical output to R8's gather-based maskprep, verified element-wise).
// ---------------------------------------------------------------------------
__global__ __launch_bounds__(256) void maskprep_kernel(
    const float* __restrict__ mask, unsigned short* __restrict__ Mf)
{
    __shared__ float lT[32][261];
    const int tid = threadIdx.x;
    const int bq = blockIdx.y;                  // b*64 + qt
    const int kx = blockIdx.x;                  // k-chunk of 256
    const float* base = mask + ((size_t)(bq >> 6) * 2048 + (bq & 63) * 32) * 2048
                        + (size_t)kx * 256;

    const int r = tid >> 3, ci = tid & 7;
    const float* rp = base + (size_t)r * 2048;
#pragma unroll
    for (int j = 0; j < 8; ++j) {
        const int c = (ci + j * 8) * 4;
        float4 v = *(const float4*)(rp + c);
        lT[r][c + 0] = v.x * L2E;
        lT[r][c + 1] = v.y * L2E;
        lT[r][c + 2] = v.z * L2E;
        lT[r][c + 3] = v.w * L2E;
    }
    __syncthreads();

    const int w = tid >> 6, lane = tid & 63;
    const int lc = lane & 31, hi = lane >> 5;
#pragma unroll
    for (int t = 0; t < 2; ++t) {
        const int ktl = w * 2 + t;
        float p[16];
#pragma unroll
        for (int jj = 0; jj < 16; ++jj)
            p[jj] = lT[lc][ktl * 32 + (jj & 3) + 8 * (jj >> 2) + 4 * hi];
        unsigned short* dst = Mf + ((size_t)bq * 64 + kx * 8 + ktl) * 1024 + lane * 16;
        *(uint4*)(dst) = make_uint4(pk2(p[0], p[1]), pk2(p[2], p[3]),
                                    pk2(p[4], p[5]), pk2(p[6], p[7]));
        *(uint4*)(dst + 8) = make_uint4(pk2(p[8], p[9]),  pk2(p[10], p[11]),
                                        pk2(p[12], p[13]), pk2(p[14], p[15]));
    }
}

// ---------------------------------------------------------------------------
// Kernel 1: flash attention, 32x32x16 MFMA, swapped QK^T (R8 structure,
// R8 arithmetic: exp2f + native pk2). grid = (16 q-tiles of 128, 32 bh);
// 4 waves x 32 q-rows. Mask C-init from Mf (coalesced bf16 fragments).
// K/V dbuf LDS (XOR swizzle), 1 barrier/tile, reg prefetch, kb-loop x2.
// ---------------------------------------------------------------------------
#define SWAP32(a, b) asm("v_permlane32_swap_b32 %0, %1" : "+v"(a), "+v"(b))

#define COMPUTE(KC, VC, M) do {                                                \
    bf16x8 pf[4];                                                              \
    _Pragma("unroll")                                                          \
    for (int kblk = 0; kblk < 2; ++kblk) {                                     \
        f32x16 z;                                                              \
        {                                                                      \
            const uint4 m0 = M[kblk][0], m1 = M[kblk][1];                      \
            z[0]  = bflo(m0.x); z[1]  = bfhi(m0.x);                            \
            z[2]  = bflo(m0.y); z[3]  = bfhi(m0.y);                            \
            z[4]  = bflo(m0.z); z[5]  = bfhi(m0.z);                            \
            z[6]  = bflo(m0.w); z[7]  = bfhi(m0.w);                            \
            z[8]  = bflo(m1.x); z[9]  = bfhi(m1.x);                            \
            z[10] = bflo(m1.y); z[11] = bfhi(m1.y);                            \
            z[12] = bflo(m1.z); z[13] = bfhi(m1.z);                            \
            z[14] = bflo(m1.w); z[15] = bfhi(m1.w);                            \
        }                                                                      \
        __builtin_amdgcn_s_setprio(1);                                         \
        _Pragma("unroll")                                                      \
        for (int s = 0; s < 4; ++s) {                                          \
            bf16x8 kf = *(const bf16x8*)((KC) + fof[kblk][s]);                 \
            z = __builtin_amdgcn_mfma_f32_32x32x16_bf16(kf, qf[s], z, 0,0,0);  \
        }                                                                      \
        __builtin_amdgcn_s_setprio(0);                                         \
        float p[16];                                                           \
        _Pragma("unroll")                                                      \
        for (int i = 0; i < 16; ++i) p[i] = exp2f(z[i]);                       \
        lsum += (((p[0]+p[1])+(p[2]+p[3])) + ((p[4]+p[5])+(p[6]+p[7])))        \
              + (((p[8]+p[9])+(p[10]+p[11])) + ((p[12]+p[13])+(p[14]+p[15]))); \
        unsigned a0 = pk2(p[0], p[1]),   b0 = pk2(p[4], p[5]);                 \
        unsigned a1 = pk2(p[2], p[3]),   b1 = pk2(p[6], p[7]);                 \
        SWAP32(a0, b0); SWAP32(a1, b1);                                        \
        union { unsigned w[4]; bf16x8 v; } u0;                                 \
        u0.w[0] = a0; u0.w[1] = a1; u0.w[2] = b0; u0.w[3] = b1;                \
        pf[kblk*2] = u0.v;                                                     \
        unsigned c0 = pk2(p[8], p[9]),   d0 = pk2(p[12], p[13]);               \
        unsigned c1 = pk2(p[10], p[11]), d1 = pk2(p[14], p[15]);               \
        SWAP32(c0, d0); SWAP32(c1, d1);                                        \
        union { unsigned w[4]; bf16x8 v; } u1;                                 \
        u1.w[0] = c0; u1.w[1] = c1; u1.w[2] = d0; u1.w[3] = d1;                \
        pf[kblk*2+1] = u1.v;                                                   \
    }                                                                          \
    __builtin_amdgcn_s_setprio(1);                                             \
    _Pragma("unroll")                                                          \
    for (int s = 0; s < 4; ++s) {                                              \
        bf16x8 vf0 = *(const bf16x8*)((VC) + fof[0][s]);                       \
        o0 = __builtin_amdgcn_mfma_f32_32x32x16_bf16(vf0, pf[s], o0, 0,0,0);   \
        bf16x8 vf1 = *(const bf16x8*)((VC) + fof[1][s]);                       \
        o1 = __builtin_amdgcn_mfma_f32_32x32x16_bf16(vf1, pf[s], o1, 0,0,0);   \
    }                                                                          \
    __builtin_amdgcn_s_setprio(0);                                             \
} while (0)

#define LOADNEXT(MD) do {                                                      \
    ka = *(const uint4*)(pgK); kc = *(const uint4*)(pgK + 8);                  \
    va = *(const uint4*)(pgV); vc = *(const uint4*)(pgV + 8);                  \
    MD[0][0] = *(const uint4*)(pmf);                                           \
    MD[0][1] = *(const uint4*)(pmf + 8);                                       \
    MD[1][0] = *(const uint4*)(pmf + 1024);                                    \
    MD[1][1] = *(const uint4*)(pmf + 1032);                                    \
    pgK += 4096; pgV += 64; pmf += 2048;                                       \
} while (0)

#define STORE(BUF) do {                                                        \
    *(uint4*)&lK[BUF][srow][su0 * 8] = ka;                                     \
    *(uint4*)&lK[BUF][srow][su1 * 8] = kc;                                     \
    *(uint4*)&lV[BUF][srow][su0 * 8] = va;                                     \
    *(uint4*)&lV[BUF][srow][su1 * 8] = vc;                                     \
} while (0)

__global__ __launch_bounds__(256, 2) void attn_kernel(
    const unsigned short* __restrict__ Qp, const unsigned short* __restrict__ Kp,
    const unsigned short* __restrict__ Vt, const unsigned short* __restrict__ Mf,
    unsigned short* __restrict__ AO)
{
    __shared__ unsigned short lK[2][64][64];   // [buf][k][d], swizzled 16B units
    __shared__ unsigned short lV[2][64][64];   // [buf][d][k], same swizzle

    const int bh = blockIdx.y;
    const int b = bh >> 3, h = bh & 7;
    const int qb = blockIdx.x * 128;
    const int tid  = threadIdx.x;
    const int lane = tid & 63, wave = tid >> 6;
    const int lc = lane & 31, hi = lane >> 5;
    const int qg = qb + wave * 32 + lc;

    // Q B-fragments: lane needs Q[qg][s*16 + hi*8 + 0..7]
    bf16x8 qf[4];
    {
        const unsigned short* qp = Qp + ((size_t)bh * 2048 + qg) * 64 + hi * 8;
#pragma unroll
        for (int s = 0; s < 4; ++s)
            qf[s] = *(const bf16x8*)(qp + s * 16);
    }

    f32x16 o0, o1;
#pragma unroll
    for (int i = 0; i < 16; ++i) { o0[i] = 0.f; o1[i] = 0.f; }
    float lsum = 0.f;

    // K/V fragment byte-offsets in a [64][64]-short tile:
    // row = blk*32 + lc; 16B-unit = (2s|hi) ^ (row&7)
    int fof[2][4];
#pragma unroll
    for (int blk = 0; blk < 2; ++blk)
#pragma unroll
        for (int s = 0; s < 4; ++s)
            fof[blk][s] = (blk * 32 + lc) * 128 +
                          ((((s << 1) | hi) ^ (lane & 7)) * 16);

    const char* lK0c = (const char*)&lK[0][0][0];
    const char* lK1c = (const char*)&lK[1][0][0];
    const char* lV0c = (const char*)&lV[0][0][0];
    const char* lV1c = (const char*)&lV[1][0][0];

    // staging: thread owns row tid>>2, 16B-units (tid&3)*2 and +1, XOR swizzle
    const int srow = tid >> 2;
    const int scu  = (tid & 3) * 2;
    const int su0  = (scu    ) ^ (srow & 7);
    const int su1  = (scu + 1) ^ (srow & 7);
    const unsigned short* pgK = Kp + (size_t)bh * 2048 * 64 + (size_t)srow * 64 + scu * 8;
    const unsigned short* pgV = Vt + (size_t)bh * 64 * 2048 + (size_t)srow * 2048 + scu * 8;
    // mask fragments: wave-uniform tile base + lane*16 shorts (coalesced)
    const unsigned short* pmf = Mf +
        ((size_t)(b * 64 + (qb >> 5) + wave) * 64) * 1024 + lane * 16;

    uint4 ka, kc, va, vc;
    uint4 mA[2][2], mB[2][2];

    // prologue: tile 0 -> LDS[0], mask tile 0 -> mA
    LOADNEXT(mA);
    STORE(0);
    __syncthreads();

    for (int kb2 = 0; kb2 < 16; ++kb2) {
        // even half: compute LDS[0]/mA, prefetch -> LDS[1]/mB
        {
            LOADNEXT(mB);
            COMPUTE(lK0c, lV0c, mA);
            STORE(1);
            __syncthreads();
        }
        // odd half: compute LDS[1]/mB, prefetch -> LDS[0]/mA
        {
            if (kb2 < 15) LOADNEXT(mA);
            COMPUTE(lK1c, lV1c, mB);
            if (kb2 < 15) {
                STORE(0);
                __syncthreads();
            }
        }
    }

    // final l reduction: halves (lane, lane^32) hold disjoint k partials
    lsum += __shfl_xor(lsum, 32);
    const float inv = 1.0f / lsum;

    // epilogue: O^T col=q, row(d) = (reg&3)+8*(reg>>2)+4*hi (+32 for o1)
    unsigned short* ao = AO + ((size_t)qg * 4 + b) * 512 + h * 64;
#pragma unroll
    for (int g = 0; g < 4; ++g) {
        const int d0 = g * 8 + hi * 4;
        *(uint2*)(ao + d0) =
            make_uint2(pk2(o0[4*g+0] * inv, o0[4*g+1] * inv),
                       pk2(o0[4*g+2] * inv, o0[4*g+3] * inv));
        *(uint2*)(ao + 32 + d0) =
            make_uint2(pk2(o1[4*g+0] * inv, o1[4*g+1] * inv),
                       pk2(o1[4*g+2] * inv, o1[4*g+3] * inv));
    }
}

// ---------------------------------------------------------------------------
// Kernel 2: output projection. out = AO(bf16) @ W_out^T + b_out (fp32 out).
// ---------------------------------------------------------------------------
__global__ __launch_bounds__(256) void oproj_kernel(
    const unsigned short* __restrict__ A, const float* __restrict__ W,
    const float* __restrict__ bias, float* __restrict__ out)
{
    __shared__ unsigned short lA[128][40];
    __shared__ unsigned short lB[128][40];

    const int rb = blockIdx.y * 128;
    const int nb = blockIdx.x * 128;
    const int tid  = threadIdx.x;
    const int lane = tid & 63, wave = tid >> 6;
    const int wr = wave >> 1, wc = wave & 1;
    const int lq = lane & 15, lg = lane >> 4;

    f32x4 acc[4][4];
#pragma unroll
    for (int i = 0; i < 4; ++i)
#pragma unroll
        for (int j = 0; j < 4; ++j) acc[i][j] = (f32x4){0.f, 0.f, 0.f, 0.f};

    const int srow = tid >> 1;
    const int scol = (tid & 1) * 16;

    for (int kt = 0; kt < 16; ++kt) {
        const int k0 = kt * 32;
        if (kt) __syncthreads();
        {
            const unsigned short* g = A + (size_t)(rb + srow) * 512 + k0 + scol;
            *(uint4*)&lA[srow][scol]     = *(const uint4*)g;
            *(uint4*)&lA[srow][scol + 8] = *(const uint4*)(g + 8);
        }
        {
            const float* g = W + (size_t)(nb + srow) * 512 + k0 + scol;
            float4 x0 = *(const float4*)(g + 0);
            float4 x1 = *(const float4*)(g + 4);
            float4 x2 = *(const float4*)(g + 8);
            float4 x3 = *(const float4*)(g + 12);
            uint4 w0, w1;
            w0.x = pk2(x0.x, x0.y); w0.y = pk2(x0.z, x0.w);
            w0.z = pk2(x1.x, x1.y); w0.w = pk2(x1.z, x1.w);
            w1.x = pk2(x2.x, x2.y); w1.y = pk2(x2.z, x2.w);
            w1.z = pk2(x3.x, x3.y); w1.w = pk2(x3.z, x3.w);
            *(uint4*)&lB[srow][scol] = w0;
            *(uint4*)&lB[srow][scol + 8] = w1;
        }
        __syncthreads();

        bf16x8 af[4], bfr[4];
#pragma unroll
        for (int mi = 0; mi < 4; ++mi)
            af[mi] = *(const bf16x8*)&lA[wr * 64 + mi * 16 + lq][lg * 8];
#pragma unroll
        for (int ni = 0; ni < 4; ++ni)
            bfr[ni] = *(const bf16x8*)&lB[wc * 64 + ni * 16 + lq][lg * 8];
#pragma unroll
        for (int mi = 0; mi < 4; ++mi)
#pragma unroll
            for (int ni = 0; ni < 4; ++ni)
                acc[mi][ni] = __builtin_amdgcn_mfma_f32_16x16x32_bf16(
                    af[mi], bfr[ni], acc[mi][ni], 0, 0, 0);
    }

#pragma unroll
    for (int ni = 0; ni < 4; ++ni) {
        const int n = nb + wc * 64 + ni * 16 + lq;
        const float bv = bias[n];
#pragma unroll
        for (int mi = 0; mi < 4; ++mi) {
#pragma unroll
            for (int r = 0; r < 4; ++r) {
                const int t = rb + wr * 64 + mi * 16 + lg * 4 + r;
                out[(size_t)t * 512 + n] = acc[mi][ni][r] + bv;
            }
        }
    }
}

extern "C" void kernel_launch(void* const* d_in, const int* in_sizes, int n_in,
                              void* d_out, int out_size, void* d_ws, size_t ws_size,
                              hipStream_t stream)
{
    (void)in_sizes; (void)n_in; (void)out_size; (void)ws_size;
    const float* query = (const float*)d_in[0];
    const float* key   = (const float*)d_in[1];
    const float* value = (const float*)d_in[2];
    const float* mask  = (const float*)d_in[3];
    const float* w_in  = (const float*)d_in[4];
    const float* b_in  = (const float*)d_in[5];
    const float* w_out = (const float*)d_in[6];
    const float* b_out = (const float*)d_in[7];
    float* out = (float*)d_out;

    char* ws = (char*)d_ws;
    unsigned short* Qp = (unsigned short*)(ws);                            // [32][2048][64]
    unsigned short* Kp = (unsigned short*)(ws + (size_t)8 * 1024 * 1024);  // [32][2048][64]
    unsigned short* Vt = (unsigned short*)(ws + (size_t)16 * 1024 * 1024); // [32][64][2048]
    unsigned short* AO = (unsigned short*)(ws + (size_t)24 * 1024 * 1024); // [8192][512]
    unsigned short* Mf = (unsigned short*)(ws + (size_t)32 * 1024 * 1024); // [4][64][64][64][16]

    qkv_kernel<<<dim3(4, 64, 3), 256, 0, stream>>>(query, key, value, w_in, b_in,
                                                   Qp, Kp, Vt);
    maskprep_kernel<<<dim3(8, 256), 256, 0, stream>>>(mask, Mf);
    attn_kernel<<<dim3(16, 32), 256, 0, stream>>>(Qp, Kp, Vt, Mf, AO);
    oproj_kernel<<<dim3(4, 64), 256, 0, stream>>>(AO, w_out, b_out, out);
}